// Round 4
// baseline (1109.897 us; speedup 1.0000x reference)
//
#include <hip/hip_runtime.h>
#include <hip/hip_bf16.h>

#define IN_C   128
#define HID    16
#define OUT_C  8
#define EDGE_C 16
#define NG     64
#define NRANGE 8   // dst ranges, pinned to XCDs via blockIdx % 8

// ---------------------------------------------------------------------------
// Shared preprocessing
// ---------------------------------------------------------------------------
__global__ void deg_kernel(const int* __restrict__ dst, int* __restrict__ deg, int E) {
    int e = blockIdx.x * blockDim.x + threadIdx.x;
    if (e < E) atomicAdd(&deg[dst[e]], 1);
}

__global__ void scanA_kernel(const int* __restrict__ deg, int* __restrict__ row_start,
                             int* __restrict__ blocksum, int n) {
    __shared__ int s[256];
    int t = threadIdx.x;
    int i = blockIdx.x * 256 + t;
    int own = (i < n) ? deg[i] : 0;
    s[t] = own; __syncthreads();
    for (int off = 1; off < 256; off <<= 1) {
        int v = (t >= off) ? s[t - off] : 0;
        __syncthreads();
        s[t] += v;
        __syncthreads();
    }
    if (i < n) row_start[i] = s[t] - own;
    if (t == 255) blocksum[blockIdx.x] = s[255];
}

__global__ void scanB_kernel(int* __restrict__ blocksum, int nb) {
    __shared__ int s[512];
    int t = threadIdx.x;
    int own = (t < nb) ? blocksum[t] : 0;
    s[t] = own; __syncthreads();
    for (int off = 1; off < 512; off <<= 1) {
        int v = (t >= off) ? s[t - off] : 0;
        __syncthreads();
        s[t] += v;
        __syncthreads();
    }
    if (t < nb) blocksum[t] = s[t] - own;
}

__global__ void scanC_kernel(const int* __restrict__ deg, int* __restrict__ row_start,
                             const int* __restrict__ blocksum,
                             int* __restrict__ cursor, float* __restrict__ dinv, int n) {
    int i = blockIdx.x * 256 + threadIdx.x;
    if (i < n) {
        int rs = row_start[i] + blocksum[blockIdx.x];
        row_start[i] = rs;
        cursor[i] = rs;
        dinv[i] = rsqrtf((float)deg[i] + 1.0f);
    }
}

__global__ void xform1_kernel(const float* __restrict__ x, const float* __restrict__ W,
                              const float* __restrict__ dinv, float* __restrict__ a1, int n) {
    int t = threadIdx.x;
    int v = blockIdx.x * 16 + (t >> 4);
    int c = t & 15;
    if (v >= n) return;
    const float4* xr = (const float4*)(x + (size_t)v * IN_C);
    float acc = 0.0f;
#pragma unroll
    for (int k4 = 0; k4 < IN_C / 4; ++k4) {
        float4 xv = xr[k4];
        int k = k4 * 4;
        acc += xv.x * W[(k + 0) * HID + c];
        acc += xv.y * W[(k + 1) * HID + c];
        acc += xv.z * W[(k + 2) * HID + c];
        acc += xv.w * W[(k + 3) * HID + c];
    }
    a1[(size_t)v * HID + c] = dinv[v] * acc;
}

__global__ void pool_final_kernel(const float* __restrict__ h2,
                                  const int* __restrict__ batch,
                                  const float* __restrict__ W, const float* __restrict__ b,
                                  float* __restrict__ out, int n) {
    __shared__ float sdata[256];
    int g = blockIdx.x;
    int t = threadIdx.x;
    int c = t & 15;
    int lo = 0, hi = n;
    while (lo < hi) { int m = (lo + hi) >> 1; if (batch[m] < g) lo = m + 1; else hi = m; }
    int start = lo;
    hi = n;
    while (lo < hi) { int m = (lo + hi) >> 1; if (batch[m] < g + 1) lo = m + 1; else hi = m; }
    int end = lo;
    float acc = 0.0f;
    for (int v = start + (t >> 4); v < end; v += 16)
        acc += h2[(size_t)v * HID + c];
    sdata[t] = acc; __syncthreads();
    for (int s = 128; s >= 16; s >>= 1) {
        if (t < s) sdata[t] += sdata[t + s];
        __syncthreads();
    }
    if (t < OUT_C) {
        float inv = 1.0f / fmaxf((float)(end - start), 1.0f);
        float o = b[t];
#pragma unroll
        for (int cc = 0; cc < HID; ++cc)
            o += sdata[cc] * inv * W[cc * OUT_C + t];
        out[g * OUT_C + t] = o;
    }
}

// ---------------------------------------------------------------------------
// Path A: CSR with materialized dinv-weighted edge rows (wea), src-only adj
// ---------------------------------------------------------------------------
// Each wea row is 16 f32 = one full 64B sector -> dense writebacks guaranteed.
__global__ void fillW_kernel(const int* __restrict__ src, const int* __restrict__ dst,
                             const float* __restrict__ edge_attr, const float* __restrict__ dinv,
                             int* __restrict__ cursor, int* __restrict__ adjsrc,
                             float* __restrict__ wea, int E, int range_size, int bpr) {
    int r = blockIdx.x & (NRANGE - 1);
    int q = blockIdx.x >> 3;
    int lo = r * range_size;
    int hi = lo + range_size;
    long long chunk = ((long long)E + bpr - 1) / bpr;
    int e0 = (int)((long long)q * chunk);
    long long e1l = (long long)e0 + chunk;
    int e1 = (e1l < E) ? (int)e1l : E;
    for (int e = e0 + threadIdx.x; e < e1; e += blockDim.x) {
        int d = dst[e];
        if (d >= lo && d < hi) {
            int s = src[e];
            int pos = atomicAdd(&cursor[d], 1);
            adjsrc[pos] = s;
            float ds = dinv[s];
            const float4* ea = (const float4*)(edge_attr + (size_t)e * EDGE_C);
            float4* wr = (float4*)(wea + (size_t)pos * EDGE_C);
            float4 v0 = ea[0], v1 = ea[1], v2 = ea[2], v3 = ea[3];
            v0.x *= ds; v0.y *= ds; v0.z *= ds; v0.w *= ds;
            v1.x *= ds; v1.y *= ds; v1.z *= ds; v1.w *= ds;
            v2.x *= ds; v2.y *= ds; v2.z *= ds; v2.w *= ds;
            v3.x *= ds; v3.y *= ds; v3.z *= ds; v3.w *= ds;
            wr[0] = v0; wr[1] = v1; wr[2] = v2; wr[3] = v3;
        }
    }
}

// Pass 1: wave per node, 4 edge-slots x 16 ch. wea stream is fully sequential.
__global__ void gather1W_kernel(const int* __restrict__ adjsrc, const int* __restrict__ row_start,
                                const int* __restrict__ deg,
                                const float* __restrict__ wea,
                                const float* __restrict__ W1e, const float* __restrict__ W2n,
                                const float* __restrict__ a1, const float* __restrict__ dinv,
                                float* __restrict__ a2, float* __restrict__ ES, int n) {
    int t = threadIdx.x;
    int lane = t & 63;
    int slot = lane >> 4;
    int c = lane & 15;
    float we[EDGE_C], wn[HID];
#pragma unroll
    for (int k = 0; k < EDGE_C; ++k) we[k] = W1e[k * HID + c];
#pragma unroll
    for (int k = 0; k < HID; ++k) wn[k] = W2n[k * HID + c];
    int v = blockIdx.x * 4 + (t >> 6);
    if (v >= n) return;
    int start = row_start[v];
    int dg = deg[v];
    float es = 0.0f, s1 = 0.0f;
    int i = slot;
    int s_next = (i < dg) ? adjsrc[start + i] : 0;
    for (; i < dg; i += 4) {
        int s = s_next;
        if (i + 4 < dg) s_next = adjsrc[start + i + 4];
        es += wea[(size_t)(start + i) * HID + c];
        s1 += a1[(size_t)s * HID + c];
    }
    es += __shfl_xor(es, 16, 64); es += __shfl_xor(es, 32, 64);
    s1 += __shfl_xor(s1, 16, 64); s1 += __shfl_xor(s1, 32, 64);
    float dv = dinv[v];
    int lanebase = lane & ~15;
    float e1 = 0.0f;
#pragma unroll
    for (int k = 0; k < EDGE_C; ++k)
        e1 += __shfl(es, lanebase + k, 64) * we[k];
    float h = fmaxf(dv * (s1 + a1[(size_t)v * HID + c] + e1), 0.0f);
    float o = 0.0f;
#pragma unroll
    for (int k = 0; k < HID; ++k)
        o += __shfl(h, lanebase + k, 64) * wn[k];
    if (slot == 0) {
        a2[(size_t)v * HID + c] = dv * o;
        ES[(size_t)v * HID + c] = es;
    }
}

// Pass 2: neighbor-sum of a2 via src-only CSR + stored ES.
__global__ void gather2W_kernel(const int* __restrict__ adjsrc, const int* __restrict__ row_start,
                                const int* __restrict__ deg,
                                const float* __restrict__ W2e,
                                const float* __restrict__ a2, const float* __restrict__ dinv,
                                const float* __restrict__ ES, float* __restrict__ h2, int n) {
    int t = threadIdx.x;
    int lane = t & 63;
    int slot = lane >> 4;
    int c = lane & 15;
    float we[EDGE_C];
#pragma unroll
    for (int k = 0; k < EDGE_C; ++k) we[k] = W2e[k * HID + c];
    int v = blockIdx.x * 4 + (t >> 6);
    if (v >= n) return;
    int start = row_start[v];
    int dg = deg[v];
    float s2 = 0.0f;
    int i = slot;
    int s_next = (i < dg) ? adjsrc[start + i] : 0;
    for (; i < dg; i += 4) {
        int s = s_next;
        if (i + 4 < dg) s_next = adjsrc[start + i + 4];
        s2 += a2[(size_t)s * HID + c];
    }
    s2 += __shfl_xor(s2, 16, 64); s2 += __shfl_xor(s2, 32, 64);
    float dv = dinv[v];
    int lanebase = lane & ~15;
    float esv = ES[(size_t)v * HID + c];
    float e2 = 0.0f;
#pragma unroll
    for (int k = 0; k < EDGE_C; ++k)
        e2 += __shfl(esv, lanebase + k, 64) * we[k];
    float h = fmaxf(dv * (s2 + a2[(size_t)v * HID + c] + e2), 0.0f);
    if (slot == 0) h2[(size_t)v * HID + c] = h;
}

// ---------------------------------------------------------------------------
// Path B (fallback, round-3 proven): int2 CSR, gather reads edge_attr by id
// ---------------------------------------------------------------------------
__global__ void fillF_kernel(const int* __restrict__ src, const int* __restrict__ dst,
                             int* __restrict__ cursor, int2* __restrict__ adj,
                             int E, int range_size, int bpr) {
    int r = blockIdx.x & (NRANGE - 1);
    int q = blockIdx.x >> 3;
    int lo = r * range_size;
    int hi = lo + range_size;
    long long chunk = ((long long)E + bpr - 1) / bpr;
    int e0 = (int)((long long)q * chunk);
    long long e1l = (long long)e0 + chunk;
    int e1 = (e1l < E) ? (int)e1l : E;
    for (int e = e0 + threadIdx.x; e < e1; e += blockDim.x) {
        int d = dst[e];
        if (d >= lo && d < hi) {
            int pos = atomicAdd(&cursor[d], 1);
            adj[pos] = make_int2(e, src[e]);
        }
    }
}

__global__ void gather1F_kernel(const int2* __restrict__ adj, const int* __restrict__ row_start,
                                const int* __restrict__ deg,
                                const float* __restrict__ edge_attr,
                                const float* __restrict__ W1e, const float* __restrict__ W2n,
                                const float* __restrict__ a1, const float* __restrict__ dinv,
                                float* __restrict__ a2, float* __restrict__ ES, int n) {
    int t = threadIdx.x;
    int lane = t & 63;
    int slot = lane >> 4;
    int c = lane & 15;
    float we[EDGE_C], wn[HID];
#pragma unroll
    for (int k = 0; k < EDGE_C; ++k) we[k] = W1e[k * HID + c];
#pragma unroll
    for (int k = 0; k < HID; ++k) wn[k] = W2n[k * HID + c];
    int v = blockIdx.x * 4 + (t >> 6);
    if (v >= n) return;
    int start = row_start[v];
    int dg = deg[v];
    float es = 0.0f, s1 = 0.0f;
    for (int i = slot; i < dg; i += 4) {
        int2 ad = adj[start + i];
        float ea = edge_attr[(size_t)ad.x * EDGE_C + c];
        float ds = dinv[ad.y];
        float av = a1[(size_t)ad.y * HID + c];
        es += ds * ea;
        s1 += av;
    }
    es += __shfl_xor(es, 16, 64); es += __shfl_xor(es, 32, 64);
    s1 += __shfl_xor(s1, 16, 64); s1 += __shfl_xor(s1, 32, 64);
    float dv = dinv[v];
    int lanebase = lane & ~15;
    float e1 = 0.0f;
#pragma unroll
    for (int k = 0; k < EDGE_C; ++k)
        e1 += __shfl(es, lanebase + k, 64) * we[k];
    float h = fmaxf(dv * (s1 + a1[(size_t)v * HID + c] + e1), 0.0f);
    float o = 0.0f;
#pragma unroll
    for (int k = 0; k < HID; ++k)
        o += __shfl(h, lanebase + k, 64) * wn[k];
    if (slot == 0) {
        a2[(size_t)v * HID + c] = dv * o;
        ES[(size_t)v * HID + c] = es;
    }
}

__global__ void gather2F_kernel(const int2* __restrict__ adj, const int* __restrict__ row_start,
                                const int* __restrict__ deg,
                                const float* __restrict__ W2e,
                                const float* __restrict__ a2, const float* __restrict__ dinv,
                                const float* __restrict__ ES, float* __restrict__ h2, int n) {
    int t = threadIdx.x;
    int lane = t & 63;
    int slot = lane >> 4;
    int c = lane & 15;
    float we[EDGE_C];
#pragma unroll
    for (int k = 0; k < EDGE_C; ++k) we[k] = W2e[k * HID + c];
    int v = blockIdx.x * 4 + (t >> 6);
    if (v >= n) return;
    int start = row_start[v];
    int dg = deg[v];
    float s2 = 0.0f;
    for (int i = slot; i < dg; i += 4) {
        int2 ad = adj[start + i];
        s2 += a2[(size_t)ad.y * HID + c];
    }
    s2 += __shfl_xor(s2, 16, 64); s2 += __shfl_xor(s2, 32, 64);
    float dv = dinv[v];
    int lanebase = lane & ~15;
    float esv = ES[(size_t)v * HID + c];
    float e2 = 0.0f;
#pragma unroll
    for (int k = 0; k < EDGE_C; ++k)
        e2 += __shfl(esv, lanebase + k, 64) * we[k];
    float h = fmaxf(dv * (s2 + a2[(size_t)v * HID + c] + e2), 0.0f);
    if (slot == 0) h2[(size_t)v * HID + c] = h;
}

// ---------------------------------------------------------------------------
extern "C" void kernel_launch(void* const* d_in, const int* in_sizes, int n_in,
                              void* d_out, int out_size, void* d_ws, size_t ws_size,
                              hipStream_t stream) {
    const float* x         = (const float*)d_in[0];
    const int*   edge_idx  = (const int*)d_in[1];
    const float* edge_attr = (const float*)d_in[2];
    const int*   batch     = (const int*)d_in[3];
    const float* W1_node   = (const float*)d_in[4];
    const float* W1_edge   = (const float*)d_in[5];
    const float* W2_node   = (const float*)d_in[6];
    const float* W2_edge   = (const float*)d_in[7];
    const float* node_W    = (const float*)d_in[8];
    const float* node_b    = (const float*)d_in[9];
    float* out = (float*)d_out;

    const int N = in_sizes[0] / IN_C;
    const int E = in_sizes[1] / 2;
    const int* src = edge_idx;
    const int* dst = edge_idx + E;

    const int tb = 256;
    const int nbN = (N + 255) / 256;
    const int range_size = (N + NRANGE - 1) / NRANGE;
    const int bpr = 128;

    // Path-A workspace requirement
    size_t needA = sizeof(float) * (size_t)EDGE_C * E        // wea
                 + sizeof(int) * (size_t)E                   // adjsrc
                 + sizeof(int) * (size_t)3 * N + 2048        // deg,row_start,cursor,blocksum
                 + sizeof(float) * (size_t)N                 // dinv
                 + sizeof(float) * (size_t)3 * HID * N;      // a1,a2,ES

    if (ws_size >= needA) {
        char* p = (char*)d_ws;
        float* wea      = (float*)p;  p += sizeof(float) * (size_t)EDGE_C * E;
        int*   adjsrc   = (int*)p;    p += sizeof(int) * (size_t)E;
        int*   deg      = (int*)p;    p += sizeof(int) * (size_t)N;
        int*   row_start= (int*)p;    p += sizeof(int) * (size_t)N;
        int*   cursor   = (int*)p;    p += sizeof(int) * (size_t)N;
        int*   blocksum = (int*)p;    p += 2048;
        float* dinv     = (float*)p;  p += sizeof(float) * (size_t)N;
        float* a1       = (float*)p;  p += sizeof(float) * (size_t)HID * N;
        float* a2       = (float*)p;  p += sizeof(float) * (size_t)HID * N;
        float* ES       = (float*)p;  p += sizeof(float) * (size_t)HID * N;
        float* h2 = a1;

        hipMemsetAsync(deg, 0, sizeof(int) * (size_t)N, stream);
        deg_kernel <<<(E + tb - 1) / tb, tb, 0, stream>>>(dst, deg, E);
        scanA_kernel<<<nbN, 256, 0, stream>>>(deg, row_start, blocksum, N);
        scanB_kernel<<<1, 512, 0, stream>>>(blocksum, nbN);
        scanC_kernel<<<nbN, 256, 0, stream>>>(deg, row_start, blocksum, cursor, dinv, N);
        fillW_kernel<<<NRANGE * bpr, tb, 0, stream>>>(src, dst, edge_attr, dinv,
                                                      cursor, adjsrc, wea, E, range_size, bpr);
        xform1_kernel<<<(N + 15) / 16, tb, 0, stream>>>(x, W1_node, dinv, a1, N);
        gather1W_kernel<<<(N + 3) / 4, tb, 0, stream>>>(
            adjsrc, row_start, deg, wea, W1_edge, W2_node, a1, dinv, a2, ES, N);
        gather2W_kernel<<<(N + 3) / 4, tb, 0, stream>>>(
            adjsrc, row_start, deg, W2_edge, a2, dinv, ES, h2, N);
        pool_final_kernel<<<NG, 256, 0, stream>>>(h2, batch, node_W, node_b, out, N);
    } else {
        // Fallback: round-3 proven path (int2 CSR, random edge_attr reads)
        char* p = (char*)d_ws;
        int2*  adj      = (int2*)p;   p += sizeof(int2) * (size_t)E;
        int*   deg      = (int*)p;    p += sizeof(int) * (size_t)N;
        int*   row_start= (int*)p;    p += sizeof(int) * (size_t)N;
        int*   cursor   = (int*)p;    p += sizeof(int) * (size_t)N;
        int*   blocksum = (int*)p;    p += 2048;
        float* dinv     = (float*)p;  p += sizeof(float) * (size_t)N;
        float* a1       = (float*)p;  p += sizeof(float) * (size_t)HID * N;
        float* a2       = (float*)p;  p += sizeof(float) * (size_t)HID * N;
        float* ES       = (float*)p;  p += sizeof(float) * (size_t)HID * N;
        float* h2 = a1;

        hipMemsetAsync(deg, 0, sizeof(int) * (size_t)N, stream);
        deg_kernel <<<(E + tb - 1) / tb, tb, 0, stream>>>(dst, deg, E);
        scanA_kernel<<<nbN, 256, 0, stream>>>(deg, row_start, blocksum, N);
        scanB_kernel<<<1, 512, 0, stream>>>(blocksum, nbN);
        scanC_kernel<<<nbN, 256, 0, stream>>>(deg, row_start, blocksum, cursor, dinv, N);
        fillF_kernel<<<NRANGE * bpr, tb, 0, stream>>>(src, dst, cursor, adj, E, range_size, bpr);
        xform1_kernel<<<(N + 15) / 16, tb, 0, stream>>>(x, W1_node, dinv, a1, N);
        gather1F_kernel<<<(N + 3) / 4, tb, 0, stream>>>(
            adj, row_start, deg, edge_attr, W1_edge, W2_node, a1, dinv, a2, ES, N);
        gather2F_kernel<<<(N + 3) / 4, tb, 0, stream>>>(
            adj, row_start, deg, W2_edge, a2, dinv, ES, h2, N);
        pool_final_kernel<<<NG, 256, 0, stream>>>(h2, batch, node_W, node_b, out, N);
    }
}

// Round 5
// 928.018 us; speedup vs baseline: 1.1960x; 1.1960x over previous
//
#include <hip/hip_runtime.h>
#include <hip/hip_bf16.h>

#define IN_C   128
#define HID    16
#define OUT_C  8
#define EDGE_C 16
#define NG     64
#define NRANGE   16   // dst ranges total (slices ~1.6MB of adj each)
#define FILL_PR  8    // ranges per fill pass (XCD-pinned via blockIdx%8)

// ---------------------------------------------------------------------------
// Partitioned in-degree histogram: 16 ranges, one pass. Blocks with
// blockIdx%16==r own range r; XCD = blockIdx%8 (heuristic) keeps each
// range's 25KB deg slice in one XCD's L2 -> no cross-XCD atomic bounce.
__global__ void deg_part_kernel(const int* __restrict__ dst, int* __restrict__ deg,
                                int E, int range_size, int bpr) {
    int r = blockIdx.x & (NRANGE - 1);
    int q = blockIdx.x >> 4;
    int lo = r * range_size;
    int hi = lo + range_size;
    long long chunk = ((long long)E + bpr - 1) / bpr;
    int e0 = (int)((long long)q * chunk);
    long long e1l = (long long)e0 + chunk;
    int e1 = (e1l < E) ? (int)e1l : E;
    for (int e = e0 + threadIdx.x; e < e1; e += blockDim.x) {
        int d = dst[e];
        if (d >= lo && d < hi) atomicAdd(&deg[d], 1);
    }
}

__global__ void scanA_kernel(const int* __restrict__ deg, int* __restrict__ row_start,
                             int* __restrict__ blocksum, int n) {
    __shared__ int s[256];
    int t = threadIdx.x;
    int i = blockIdx.x * 256 + t;
    int own = (i < n) ? deg[i] : 0;
    s[t] = own; __syncthreads();
    for (int off = 1; off < 256; off <<= 1) {
        int v = (t >= off) ? s[t - off] : 0;
        __syncthreads();
        s[t] += v;
        __syncthreads();
    }
    if (i < n) row_start[i] = s[t] - own;
    if (t == 255) blocksum[blockIdx.x] = s[255];
}

__global__ void scanB_kernel(int* __restrict__ blocksum, int nb) {
    __shared__ int s[512];
    int t = threadIdx.x;
    int own = (t < nb) ? blocksum[t] : 0;
    s[t] = own; __syncthreads();
    for (int off = 1; off < 512; off <<= 1) {
        int v = (t >= off) ? s[t - off] : 0;
        __syncthreads();
        s[t] += v;
        __syncthreads();
    }
    if (t < nb) blocksum[t] = s[t] - own;
}

__global__ void scanC_kernel(const int* __restrict__ deg, int* __restrict__ row_start,
                             const int* __restrict__ blocksum,
                             int* __restrict__ cursor, float* __restrict__ dinv, int n) {
    int i = blockIdx.x * 256 + threadIdx.x;
    if (i < n) {
        int rs = row_start[i] + blocksum[blockIdx.x];
        row_start[i] = rs;
        cursor[i] = rs;
        dinv[i] = rsqrtf((float)deg[i] + 1.0f);
    }
}

// CSR fill, 8 XCD-pinned ranges per pass (pass selects range block 0..7 or 8..15).
// Active adj slice per XCD = ~1.6MB -> lines collect all 16 int2 before writeback.
__global__ void fill_kernel(const int* __restrict__ src, const int* __restrict__ dst,
                            int* __restrict__ cursor, int2* __restrict__ adj,
                            int E, int range_size, int bpr, int pass) {
    int r = (blockIdx.x & (FILL_PR - 1)) + pass * FILL_PR;
    int q = blockIdx.x >> 3;
    int lo = r * range_size;
    int hi = lo + range_size;
    long long chunk = ((long long)E + bpr - 1) / bpr;
    int e0 = (int)((long long)q * chunk);
    long long e1l = (long long)e0 + chunk;
    int e1 = (e1l < E) ? (int)e1l : E;
    for (int e = e0 + threadIdx.x; e < e1; e += blockDim.x) {
        int d = dst[e];
        if (d >= lo && d < hi) {
            int pos = atomicAdd(&cursor[d], 1);
            adj[pos] = make_int2(e, src[e]);
        }
    }
}

__global__ void xform1_kernel(const float* __restrict__ x, const float* __restrict__ W,
                              const float* __restrict__ dinv, float* __restrict__ a1, int n) {
    int t = threadIdx.x;
    int v = blockIdx.x * 16 + (t >> 4);
    int c = t & 15;
    if (v >= n) return;
    const float4* xr = (const float4*)(x + (size_t)v * IN_C);
    float acc = 0.0f;
#pragma unroll
    for (int k4 = 0; k4 < IN_C / 4; ++k4) {
        float4 xv = xr[k4];
        int k = k4 * 4;
        acc += xv.x * W[(k + 0) * HID + c];
        acc += xv.y * W[(k + 1) * HID + c];
        acc += xv.z * W[(k + 2) * HID + c];
        acc += xv.w * W[(k + 3) * HID + c];
    }
    a1[(size_t)v * HID + c] = dinv[v] * acc;
}

// Pass 1: wave per node, 4 edge-slots x 16 ch, 2x unrolled software pipeline
// (adj prefetched 2 steps ahead; 2 independent ea/a1 loads in flight per slot).
//   ES[v][c] = sum_e dinv[s]*ea[e][c]  (layer-independent, stored)
//   h1 = relu(dinv[v]*(S1 + a1[v] + ES@W1e));  a2[v] = dinv[v]*(h1@W2n)
__global__ void gather1_kernel(const int2* __restrict__ adj, const int* __restrict__ row_start,
                               const int* __restrict__ deg,
                               const float* __restrict__ edge_attr,
                               const float* __restrict__ W1e, const float* __restrict__ W2n,
                               const float* __restrict__ a1, const float* __restrict__ dinv,
                               float* __restrict__ a2, float* __restrict__ ES, int n) {
    int t = threadIdx.x;
    int lane = t & 63;
    int slot = lane >> 4;
    int c = lane & 15;
    float we[EDGE_C], wn[HID];
#pragma unroll
    for (int k = 0; k < EDGE_C; ++k) we[k] = W1e[k * HID + c];
#pragma unroll
    for (int k = 0; k < HID; ++k) wn[k] = W2n[k * HID + c];
    int v = blockIdx.x * 4 + (t >> 6);
    if (v >= n) return;
    int start = row_start[v];
    int dg = deg[v];
    float es = 0.0f, s1 = 0.0f;
    int i = slot;
    int2 ad0 = (i     < dg) ? adj[start + i]     : make_int2(0, 0);
    int2 ad1 = (i + 4 < dg) ? adj[start + i + 4] : make_int2(0, 0);
    for (; i < dg; i += 8) {
        int2 nad0 = (i +  8 < dg) ? adj[start + i +  8] : make_int2(0, 0);
        int2 nad1 = (i + 12 < dg) ? adj[start + i + 12] : make_int2(0, 0);
        float ea0 = edge_attr[(size_t)ad0.x * EDGE_C + c];
        float a10 = a1[(size_t)ad0.y * HID + c];
        float ds0 = dinv[ad0.y];
        bool  ok1 = (i + 4 < dg);
        float ea1 = ok1 ? edge_attr[(size_t)ad1.x * EDGE_C + c] : 0.0f;
        float a11 = ok1 ? a1[(size_t)ad1.y * HID + c] : 0.0f;
        float ds1 = ok1 ? dinv[ad1.y] : 0.0f;
        es += ds0 * ea0 + ds1 * ea1;
        s1 += a10 + a11;
        ad0 = nad0; ad1 = nad1;
    }
    es += __shfl_xor(es, 16, 64); es += __shfl_xor(es, 32, 64);
    s1 += __shfl_xor(s1, 16, 64); s1 += __shfl_xor(s1, 32, 64);
    float dv = dinv[v];
    int lanebase = lane & ~15;
    float e1 = 0.0f;
#pragma unroll
    for (int k = 0; k < EDGE_C; ++k)
        e1 += __shfl(es, lanebase + k, 64) * we[k];
    float h = fmaxf(dv * (s1 + a1[(size_t)v * HID + c] + e1), 0.0f);
    float o = 0.0f;
#pragma unroll
    for (int k = 0; k < HID; ++k)
        o += __shfl(h, lanebase + k, 64) * wn[k];
    if (slot == 0) {
        a2[(size_t)v * HID + c] = dv * o;
        ES[(size_t)v * HID + c] = es;
    }
}

// Pass 2: neighbor-sum of a2 (no edge_attr) + stored ES, same pipeline.
__global__ void gather2_kernel(const int2* __restrict__ adj, const int* __restrict__ row_start,
                               const int* __restrict__ deg,
                               const float* __restrict__ W2e,
                               const float* __restrict__ a2, const float* __restrict__ dinv,
                               const float* __restrict__ ES, float* __restrict__ h2, int n) {
    int t = threadIdx.x;
    int lane = t & 63;
    int slot = lane >> 4;
    int c = lane & 15;
    float we[EDGE_C];
#pragma unroll
    for (int k = 0; k < EDGE_C; ++k) we[k] = W2e[k * HID + c];
    int v = blockIdx.x * 4 + (t >> 6);
    if (v >= n) return;
    int start = row_start[v];
    int dg = deg[v];
    float s2 = 0.0f;
    int i = slot;
    int2 ad0 = (i     < dg) ? adj[start + i]     : make_int2(0, 0);
    int2 ad1 = (i + 4 < dg) ? adj[start + i + 4] : make_int2(0, 0);
    for (; i < dg; i += 8) {
        int2 nad0 = (i +  8 < dg) ? adj[start + i +  8] : make_int2(0, 0);
        int2 nad1 = (i + 12 < dg) ? adj[start + i + 12] : make_int2(0, 0);
        float v0 = a2[(size_t)ad0.y * HID + c];
        bool  ok1 = (i + 4 < dg);
        float v1 = ok1 ? a2[(size_t)ad1.y * HID + c] : 0.0f;
        s2 += v0 + v1;
        ad0 = nad0; ad1 = nad1;
    }
    s2 += __shfl_xor(s2, 16, 64); s2 += __shfl_xor(s2, 32, 64);
    float dv = dinv[v];
    int lanebase = lane & ~15;
    float esv = ES[(size_t)v * HID + c];
    float e2 = 0.0f;
#pragma unroll
    for (int k = 0; k < EDGE_C; ++k)
        e2 += __shfl(esv, lanebase + k, 64) * we[k];
    float h = fmaxf(dv * (s2 + a2[(size_t)v * HID + c] + e2), 0.0f);
    if (slot == 0) h2[(size_t)v * HID + c] = h;
}

__global__ void pool_final_kernel(const float* __restrict__ h2,
                                  const int* __restrict__ batch,
                                  const float* __restrict__ W, const float* __restrict__ b,
                                  float* __restrict__ out, int n) {
    __shared__ float sdata[256];
    int g = blockIdx.x;
    int t = threadIdx.x;
    int c = t & 15;
    int lo = 0, hi = n;
    while (lo < hi) { int m = (lo + hi) >> 1; if (batch[m] < g) lo = m + 1; else hi = m; }
    int start = lo;
    hi = n;
    while (lo < hi) { int m = (lo + hi) >> 1; if (batch[m] < g + 1) lo = m + 1; else hi = m; }
    int end = lo;
    float acc = 0.0f;
    for (int v = start + (t >> 4); v < end; v += 16)
        acc += h2[(size_t)v * HID + c];
    sdata[t] = acc; __syncthreads();
    for (int s = 128; s >= 16; s >>= 1) {
        if (t < s) sdata[t] += sdata[t + s];
        __syncthreads();
    }
    if (t < OUT_C) {
        float inv = 1.0f / fmaxf((float)(end - start), 1.0f);
        float o = b[t];
#pragma unroll
        for (int cc = 0; cc < HID; ++cc)
            o += sdata[cc] * inv * W[cc * OUT_C + t];
        out[g * OUT_C + t] = o;
    }
}

// ---------------------------------------------------------------------------
extern "C" void kernel_launch(void* const* d_in, const int* in_sizes, int n_in,
                              void* d_out, int out_size, void* d_ws, size_t ws_size,
                              hipStream_t stream) {
    const float* x         = (const float*)d_in[0];
    const int*   edge_idx  = (const int*)d_in[1];
    const float* edge_attr = (const float*)d_in[2];
    const int*   batch     = (const int*)d_in[3];
    const float* W1_node   = (const float*)d_in[4];
    const float* W1_edge   = (const float*)d_in[5];
    const float* W2_node   = (const float*)d_in[6];
    const float* W2_edge   = (const float*)d_in[7];
    const float* node_W    = (const float*)d_in[8];
    const float* node_b    = (const float*)d_in[9];
    float* out = (float*)d_out;

    const int N = in_sizes[0] / IN_C;
    const int E = in_sizes[1] / 2;
    const int* src = edge_idx;
    const int* dst = edge_idx + E;

    char* p = (char*)d_ws;
    int2*  adj      = (int2*)p;   p += sizeof(int2) * (size_t)E;
    int*   deg      = (int*)p;    p += sizeof(int) * (size_t)N;   // zeroed
    int*   row_start= (int*)p;    p += sizeof(int) * (size_t)N;
    int*   cursor   = (int*)p;    p += sizeof(int) * (size_t)N;
    int*   blocksum = (int*)p;    p += 2048;
    float* dinv     = (float*)p;  p += sizeof(float) * (size_t)N;
    float* a1       = (float*)p;  p += sizeof(float) * (size_t)HID * N;
    float* a2       = (float*)p;  p += sizeof(float) * (size_t)HID * N;
    float* ES       = (float*)p;  p += sizeof(float) * (size_t)HID * N;
    float* h2 = a1;   // a1 dead after gather1

    hipMemsetAsync(deg, 0, sizeof(int) * (size_t)N, stream);

    const int tb = 256;
    const int nbN = (N + 255) / 256;
    const int range_size = (N + NRANGE - 1) / NRANGE;   // 6250

    const int bprD = 64;    // 16 ranges x 64 = 1024 blocks
    deg_part_kernel<<<NRANGE * bprD, tb, 0, stream>>>(dst, deg, E, range_size, bprD);

    scanA_kernel<<<nbN, 256, 0, stream>>>(deg, row_start, blocksum, N);
    scanB_kernel<<<1, 512, 0, stream>>>(blocksum, nbN);
    scanC_kernel<<<nbN, 256, 0, stream>>>(deg, row_start, blocksum, cursor, dinv, N);

    const int bprF = 128;   // 8 ranges x 128 = 1024 blocks per pass
    fill_kernel<<<FILL_PR * bprF, tb, 0, stream>>>(src, dst, cursor, adj, E, range_size, bprF, 0);
    fill_kernel<<<FILL_PR * bprF, tb, 0, stream>>>(src, dst, cursor, adj, E, range_size, bprF, 1);

    xform1_kernel<<<(N + 15) / 16, tb, 0, stream>>>(x, W1_node, dinv, a1, N);

    gather1_kernel<<<(N + 3) / 4, tb, 0, stream>>>(
        adj, row_start, deg, edge_attr, W1_edge, W2_node, a1, dinv, a2, ES, N);
    gather2_kernel<<<(N + 3) / 4, tb, 0, stream>>>(
        adj, row_start, deg, W2_edge, a2, dinv, ES, h2, N);

    pool_final_kernel<<<NG, 256, 0, stream>>>(h2, batch, node_W, node_b, out, N);
}